// Round 18
// baseline (205.542 us; speedup 1.0000x reference)
//
#include <hip/hip_runtime.h>

#define HH 1024
#define WW 1024
#define NIMG 12
#define OUTC 50            // output cols per wave (lanes 7..56)
#define NSTRIP 21          // ceil(1024/50)
#define TROWS 79           // 64 output rows + 15 halo rows per block tile

// fwd8: F(l) = sum of values at lanes l..l+7 (valid for lane <= 56), balanced
// pairwise tree — identical grouping to all previous rounds (bitwise-stable).
__device__ __forceinline__ float fwd8(float a) {
  a += __shfl_down(a, 1, 64);
  a += __shfl_down(a, 2, 64);
  a += __shfl_down(a, 4, 64);
  return a;
}

// first-wins argmin combine: keep a unless |b| strictly smaller (tie -> a).
__device__ __forceinline__ float winner(float a, float b) {
  return (fabsf(b) < fabsf(a)) ? b : a;
}

__device__ __forceinline__ float out_px(float ua, float ub, float uc,
                                        float da, float db, float dc,
                                        float lh0, float rh0, float w0) {
  const float ih = 1.0f / 120.0f, iq = 1.0f / 64.0f;
  const float nw0 = -w0;
  const float Ls = ua + da - lh0;
  const float Rs = ub + db - rh0;
  const float Us = ua + ub - uc;
  const float Ds = da + db - dc;
  float d0 = fmaf(Ls, ih, nw0);
  float d1 = fmaf(Rs, ih, nw0);
  float d2 = fmaf(Us, ih, nw0);
  float d3 = fmaf(Ds, ih, nw0);
  float d4 = fmaf(ua, iq, nw0);
  float d5 = fmaf(ub, iq, nw0);
  float d6 = fmaf(da, iq, nw0);
  float d7 = fmaf(db, iq, nw0);
  float w01 = winner(d0, d1), w23 = winner(d2, d3);
  float w45 = winner(d4, d5), w67 = winner(d6, d7);
  float bd = winner(winner(w01, w23), winner(w45, w67));
  return w0 + bd;
}

// One SWF step. Block = 4 waves x one 64-col span x 64 contiguous output rows
// (16 rows/wave). Tile 79x64 = 20.2 KB -> 8 blocks/CU (32 waves/CU, 100% cap)
// vs R17's 36.9 KB (4 blocks/CU, 50% cap). Prologue re-reads are LDS-cheap, so
// the 16-row amortization penalty (~10% VALU) buys up to 2.5x resident waves.
// Main-loop arithmetic identical to R15/R17 -> bitwise-identical output.
__global__ __launch_bounds__(256, 8) void swf_step(const float* __restrict__ src,
                                                   float* __restrict__ dst) {
  const int lane = threadIdx.x & 63;
  const int wid  = threadIdx.x >> 6;
  const int cl   = blockIdx.x * OUTC - 7 + lane;       // lane's col (load col)
  const int yb0  = blockIdx.y * 64;                    // block's first output row
  const int y0   = yb0 + wid * 16;                     // wave's first output row
  const float* s = src + (size_t)blockIdx.z * HH * WW;
  float* d       = dst + (size_t)blockIdx.z * HH * WW;

  const bool colOK   = ((unsigned)cl < (unsigned)WW);
  const bool writeOK = (lane >= 7) && (lane <= 56) && colOK;

  __shared__ float tile[TROWS][64];

  // ---- stage block tile: global rows yb0-8 .. yb0+70 (clamped), strip cols
  {
    const int clg = min(max(cl, 0), WW - 1);           // per-lane clamped col
    const int rb  = wid * 20;
    const int re  = (wid == 3) ? TROWS : rb + 20;      // 20,20,20,19 rows
    for (int r = rb; r < re; ++r) {
      const int gr  = yb0 - 8 + r;
      const int grc = min(max(gr, 0), HH - 1);         // wave-uniform clamped row
      const float* gp = s + (size_t)grc * WW + clg;    // per-lane global addr
      __builtin_amdgcn_global_load_lds(
          (const __attribute__((address_space(1))) void*)gp,
          (__attribute__((address_space(3))) void*)&tile[r][0],
          4, 0, 0);
    }
  }
  asm volatile("s_waitcnt vmcnt(0)" ::: "memory");
  __syncthreads();   // one-time; tile is read-only afterwards

  // tile pixel for this lane at global row ry; zero outside the image.
  #define TP(ry) ( ((unsigned)(ry) < (unsigned)HH && colOK) \
                     ? tile[(ry) - yb0 + 8][lane] : 0.0f )

  float rlh[16], rrh[16], rw[16];

  // Prologue: rows y0-8 .. y0+6 into slot row&15 = (j+8)&15 (y0 % 16 == 0).
  #pragma unroll
  for (int j = 0; j < 15; ++j) {
    const int slot = (j + 8) & 15;
    float wc = TP(y0 - 8 + j);
    float f  = fwd8(wc);
    rlh[slot] = __shfl_up(f, 7, 64);
    rrh[slot] = f;
    rw [slot] = wc;
  }

  // Sliding accumulators for "previous output row" y0-1:
  //   u* over rows y0-8..y0-1 (slots 8..15), d* over rows y0-1..y0+6 (15,0..6)
  float ua = 0.f, ub = 0.f, uc = 0.f, da = 0.f, db = 0.f, dc = 0.f;
  #pragma unroll
  for (int j = 0; j < 8; ++j) {
    const int sl = (8 + j) & 15;
    ua += rlh[sl]; ub += rrh[sl]; uc += rw[sl];
  }
  #pragma unroll
  for (int j = 0; j < 8; ++j) {
    const int sl = (15 + j) & 15;
    da += rlh[sl]; db += rrh[sl]; dc += rw[sl];
  }

  #pragma unroll
  for (int i = 0; i < 16; i += 2) {   // rows y, y+1 (8 pairs, fully unrolled)
    const int y = y0 + i;

    const int ls0 = (i + 7) & 15;
    const int ls1 = (i + 8) & 15;

    // rows y+7, y+8 from LDS: two independent fwd8 chains
    const float t0 = TP(y + 7);
    const float t1 = TP(y + 8);
    float f0 = fwd8(t0);
    float f1 = fwd8(t1);
    float l0 = __shfl_up(f0, 7, 64);
    float l1 = __shfl_up(f1, 7, 64);

    // commit row y+7 (slot ls0 held dead row y-9)
    rlh[ls0] = l0; rrh[ls0] = f0; rw[ls0] = t0;
    // row y+8 stays in temps: slot ls1 still live (row y-8, read below)

    // ---- row y: slide windows y-1 -> y (reads OLD slot ls1 = row y-8)
    ua += rlh[i];   ua -= rlh[ls1];
    ub += rrh[i];   ub -= rrh[ls1];
    uc += rw [i];   uc -= rw [ls1];
    da += rlh[ls0]; da -= rlh[(i + 15) & 15];
    db += rrh[ls0]; db -= rrh[(i + 15) & 15];
    dc += rw [ls0]; dc -= rw [(i + 15) & 15];
    const float o0 = out_px(ua, ub, uc, da, db, dc, rlh[i], rrh[i], rw[i]);

    // commit row y+8 (row y-8 now dead)
    rlh[ls1] = l1; rrh[ls1] = f1; rw[ls1] = t1;

    // ---- row y+1: slide windows y -> y+1
    const int i1 = i + 1;
    ua += rlh[i1];  ua -= rlh[(i1 + 8) & 15];
    ub += rrh[i1];  ub -= rrh[(i1 + 8) & 15];
    uc += rw [i1];  uc -= rw [(i1 + 8) & 15];
    da += rlh[ls1]; da -= rlh[i];
    db += rrh[ls1]; db -= rrh[i];
    dc += rw [ls1]; dc -= rw [i];
    const float o1 = out_px(ua, ub, uc, da, db, dc, rlh[i1], rrh[i1], rw[i1]);

    if (writeOK) {
      d[(size_t)y * WW + cl]       = o0;
      d[(size_t)(y + 1) * WW + cl] = o1;
    }
  }
  #undef TP
}

extern "C" void kernel_launch(void* const* d_in, const int* in_sizes, int n_in,
                              void* d_out, int out_size, void* d_ws, size_t ws_size,
                              hipStream_t stream) {
  const float* in = (const float*)d_in[0];
  float* out = (float*)d_out;
  float* ws  = (float*)d_ws;   // 12*1024*1024*4 = 50.3 MB scratch

  dim3 grid(NSTRIP, 16, NIMG);  // 21 col-strips, 16 row-blocks x 64 rows, 12 planes
  dim3 block(256);

  swf_step<<<grid, block, 0, stream>>>(in, out);
  swf_step<<<grid, block, 0, stream>>>(out, ws);
  swf_step<<<grid, block, 0, stream>>>(ws, out);
}

// Round 19
// 127.130 us; speedup vs baseline: 1.6168x; 1.6168x over previous
//
#include <hip/hip_runtime.h>

#define HH 1024
#define WW 1024
#define NIMG 12
#define OUTC 50            // output cols per wave (lanes 7..56)
#define NSTRIP 21          // ceil(1024/50)
#define TROWS 79           // 64 output rows + 15 halo rows per block tile

// fwd8: F(l) = sum of values at lanes l..l+7 (valid for lane <= 56), balanced
// pairwise tree — identical grouping to all previous rounds (bitwise-stable).
__device__ __forceinline__ float fwd8(float a) {
  a += __shfl_down(a, 1, 64);
  a += __shfl_down(a, 2, 64);
  a += __shfl_down(a, 4, 64);
  return a;
}

// first-wins argmin combine: keep a unless |b| strictly smaller (tie -> a).
__device__ __forceinline__ float winner(float a, float b) {
  return (fabsf(b) < fabsf(a)) ? b : a;
}

__device__ __forceinline__ float out_px(float ua, float ub, float uc,
                                        float da, float db, float dc,
                                        float lh0, float rh0, float w0) {
  const float ih = 1.0f / 120.0f, iq = 1.0f / 64.0f;
  const float nw0 = -w0;
  const float Ls = ua + da - lh0;
  const float Rs = ub + db - rh0;
  const float Us = ua + ub - uc;
  const float Ds = da + db - dc;
  float d0 = fmaf(Ls, ih, nw0);
  float d1 = fmaf(Rs, ih, nw0);
  float d2 = fmaf(Us, ih, nw0);
  float d3 = fmaf(Ds, ih, nw0);
  float d4 = fmaf(ua, iq, nw0);
  float d5 = fmaf(ub, iq, nw0);
  float d6 = fmaf(da, iq, nw0);
  float d7 = fmaf(db, iq, nw0);
  float w01 = winner(d0, d1), w23 = winner(d2, d3);
  float w45 = winner(d4, d5), w67 = winner(d6, d7);
  float bd = winner(winner(w01, w23), winner(w45, w67));
  return w0 + bd;
}

// One SWF step. Block = 4 waves x one 64-col span x 64 output rows (16/wave).
// Tile 79x64 = 20480 B -> 8 blocks/CU possible (8 x 20480 = exactly 160 KB),
// 100% occupancy cap, IF natural VGPR <= 64 (it has been 52-60 un-forced).
// NO launch_bounds register force (R18's (256,8) caused a spill cascade:
// VGPR 32, +80MB scratch writes). OOB rows/cols are ZERO-STAGED into the
// tile, so in-loop reads are bare ds_reads (no compare/cndmask per read).
__global__ __launch_bounds__(256, 4) void swf_step(const float* __restrict__ src,
                                                   float* __restrict__ dst) {
  const int lane = threadIdx.x & 63;
  const int wid  = threadIdx.x >> 6;
  const int cl   = blockIdx.x * OUTC - 7 + lane;       // lane's col (load col)
  const int yb0  = blockIdx.y * 64;                    // block's first output row
  const int y0   = yb0 + wid * 16;                     // wave's first output row
  const float* s = src + (size_t)blockIdx.z * HH * WW;
  float* d       = dst + (size_t)blockIdx.z * HH * WW;

  const bool colOK   = ((unsigned)cl < (unsigned)WW);
  const bool writeOK = (lane >= 7) && (lane <= 56) && colOK;

  __shared__ float tile[TROWS][64];

  // ---- stage block tile rows yb0-8 .. yb0+70; OOB rows/cols become zeros
  {
    const int clg = min(max(cl, 0), WW - 1);           // per-lane safe col
    const int rb  = wid * 20;
    const int re  = (wid == 3) ? TROWS : rb + 20;      // 20,20,20,19 rows
    for (int r = rb; r < re; ++r) {
      const int gr = yb0 - 8 + r;
      if ((unsigned)gr < (unsigned)HH) {               // wave-uniform branch
        const float* gp = s + (size_t)gr * WW + clg;   // per-lane global addr
        __builtin_amdgcn_global_load_lds(
            (const __attribute__((address_space(1))) void*)gp,
            (__attribute__((address_space(3))) void*)&tile[r][0],
            4, 0, 0);
      } else {
        tile[r][lane] = 0.0f;                          // OOB row -> zeros
      }
    }
    asm volatile("s_waitcnt vmcnt(0)" ::: "memory");   // my DMA rows landed
    if (!colOK) {                                      // OOB col -> zero my column
      for (int r = rb; r < re; ++r) tile[r][lane] = 0.0f;
    }
  }
  __syncthreads();   // one-time; tile is read-only afterwards

  // tile pixel for this lane at global row ry (bare LDS read; zeros pre-staged)
  #define TP(ry) ( tile[(ry) - yb0 + 8][lane] )

  float rlh[16], rrh[16], rw[16];

  // Prologue: rows y0-8 .. y0+6 into slot row&15 = (j+8)&15 (y0 % 16 == 0).
  #pragma unroll
  for (int j = 0; j < 15; ++j) {
    const int slot = (j + 8) & 15;
    float wc = TP(y0 - 8 + j);
    float f  = fwd8(wc);
    rlh[slot] = __shfl_up(f, 7, 64);
    rrh[slot] = f;
    rw [slot] = wc;
  }

  // Sliding accumulators for "previous output row" y0-1:
  //   u* over rows y0-8..y0-1 (slots 8..15), d* over rows y0-1..y0+6 (15,0..6)
  float ua = 0.f, ub = 0.f, uc = 0.f, da = 0.f, db = 0.f, dc = 0.f;
  #pragma unroll
  for (int j = 0; j < 8; ++j) {
    const int sl = (8 + j) & 15;
    ua += rlh[sl]; ub += rrh[sl]; uc += rw[sl];
  }
  #pragma unroll
  for (int j = 0; j < 8; ++j) {
    const int sl = (15 + j) & 15;
    da += rlh[sl]; db += rrh[sl]; dc += rw[sl];
  }

  #pragma unroll
  for (int i = 0; i < 16; i += 2) {   // rows y, y+1 (8 pairs, fully unrolled)
    const int y = y0 + i;

    const int ls0 = (i + 7) & 15;
    const int ls1 = (i + 8) & 15;

    // rows y+7, y+8 from LDS: two independent fwd8 chains
    const float t0 = TP(y + 7);
    const float t1 = TP(y + 8);
    float f0 = fwd8(t0);
    float f1 = fwd8(t1);
    float l0 = __shfl_up(f0, 7, 64);
    float l1 = __shfl_up(f1, 7, 64);

    // commit row y+7 (slot ls0 held dead row y-9)
    rlh[ls0] = l0; rrh[ls0] = f0; rw[ls0] = t0;
    // row y+8 stays in temps: slot ls1 still live (row y-8, read below)

    // ---- row y: slide windows y-1 -> y (reads OLD slot ls1 = row y-8)
    ua += rlh[i];   ua -= rlh[ls1];
    ub += rrh[i];   ub -= rrh[ls1];
    uc += rw [i];   uc -= rw [ls1];
    da += rlh[ls0]; da -= rlh[(i + 15) & 15];
    db += rrh[ls0]; db -= rrh[(i + 15) & 15];
    dc += rw [ls0]; dc -= rw [(i + 15) & 15];
    const float o0 = out_px(ua, ub, uc, da, db, dc, rlh[i], rrh[i], rw[i]);

    // commit row y+8 (row y-8 now dead)
    rlh[ls1] = l1; rrh[ls1] = f1; rw[ls1] = t1;

    // ---- row y+1: slide windows y -> y+1
    const int i1 = i + 1;
    ua += rlh[i1];  ua -= rlh[(i1 + 8) & 15];
    ub += rrh[i1];  ub -= rrh[(i1 + 8) & 15];
    uc += rw [i1];  uc -= rw [(i1 + 8) & 15];
    da += rlh[ls1]; da -= rlh[i];
    db += rrh[ls1]; db -= rrh[i];
    dc += rw [ls1]; dc -= rw [i];
    const float o1 = out_px(ua, ub, uc, da, db, dc, rlh[i1], rrh[i1], rw[i1]);

    if (writeOK) {
      d[(size_t)y * WW + cl]       = o0;
      d[(size_t)(y + 1) * WW + cl] = o1;
    }
  }
  #undef TP
}

extern "C" void kernel_launch(void* const* d_in, const int* in_sizes, int n_in,
                              void* d_out, int out_size, void* d_ws, size_t ws_size,
                              hipStream_t stream) {
  const float* in = (const float*)d_in[0];
  float* out = (float*)d_out;
  float* ws  = (float*)d_ws;   // 12*1024*1024*4 = 50.3 MB scratch

  dim3 grid(NSTRIP, 16, NIMG);  // 21 col-strips, 16 row-blocks x 64 rows, 12 planes
  dim3 block(256);

  swf_step<<<grid, block, 0, stream>>>(in, out);
  swf_step<<<grid, block, 0, stream>>>(out, ws);
  swf_step<<<grid, block, 0, stream>>>(ws, out);
}